// Round 1
// baseline (559.701 us; speedup 1.0000x reference)
//
#include <hip/hip_runtime.h>

#define N_NODES 10000
#define E_EDGES 150000
#define KNB     15

// ---------------------------------------------------------------------------
// CSR build: count -> scan -> fill (groups edge_attr scalars by src node)
// ---------------------------------------------------------------------------
__global__ void count_kernel(const int* __restrict__ idxs, int* __restrict__ cnt, int e) {
    int i = blockIdx.x * blockDim.x + threadIdx.x;
    if (i < e) atomicAdd(&cnt[idxs[i]], 1);
}

__global__ void scan_kernel(const int* __restrict__ cnt, int* __restrict__ eoff, int n) {
    __shared__ int lds[1024];
    __shared__ int carry_s;
    if (threadIdx.x == 0) carry_s = 0;
    __syncthreads();
    for (int base = 0; base < n; base += 1024) {
        int i = base + (int)threadIdx.x;
        int v = (i < n) ? cnt[i] : 0;
        lds[threadIdx.x] = v;
        __syncthreads();
        for (int off = 1; off < 1024; off <<= 1) {
            int t = 0;
            if (threadIdx.x >= (unsigned)off) t = lds[threadIdx.x - off];
            __syncthreads();
            if (threadIdx.x >= (unsigned)off) lds[threadIdx.x] += t;
            __syncthreads();
        }
        int incl  = lds[threadIdx.x];
        int total = lds[1023];
        if (i < n) eoff[i] = carry_s + incl - v;   // exclusive prefix
        __syncthreads();
        if (threadIdx.x == 0) carry_s += total;
        __syncthreads();
    }
}

__global__ void fill_kernel(const int* __restrict__ idxs, const float* __restrict__ ea,
                            const int* __restrict__ eoff, int* __restrict__ fill,
                            float* __restrict__ eas, int e) {
    int i = blockIdx.x * blockDim.x + threadIdx.x;
    if (i < e) {
        int s = idxs[i];
        int p = atomicAdd(&fill[s], 1);
        eas[eoff[s] + p] = ea[i];
    }
}

// ---------------------------------------------------------------------------
// Per-node message reduce: meanh[n][d] = mean_e relu(u[n][d] + ea_e * w[d])
// ---------------------------------------------------------------------------
__global__ __launch_bounds__(128)
void msg_reduce_kernel(const float* __restrict__ u, const float* __restrict__ wlast,
                       const float* __restrict__ eas, const int* __restrict__ eoff,
                       const int* __restrict__ cnt, float* __restrict__ meanh,
                       float* __restrict__ maskv) {
    int n = blockIdx.x, d = threadIdx.x;
    __shared__ float es[128];
    int c = cnt[n], base = eoff[n];
    float uu = u[n * 128 + d];
    float w  = wlast[d];
    float s  = 0.f;
    for (int st = 0; st < c; st += 128) {
        __syncthreads();
        if (st + d < c) es[d] = eas[base + st + d];
        __syncthreads();
        int m = min(128, c - st);
        for (int j = 0; j < m; ++j) s += fmaxf(fmaf(es[j], w, uu), 0.f);
    }
    meanh[n * 128 + d] = (c > 0) ? s / (float)c : 0.f;
    if (d == 0) maskv[n] = (c > 0) ? 1.f : 0.f;
}

// ---------------------------------------------------------------------------
// Weight-fold: Mout[128x128] = A[128xKa] @ B[Kax128]; vout[j] = sum_k b2[k]*B[k][j]
// ---------------------------------------------------------------------------
__global__ __launch_bounds__(256)
void wmix_kernel(const float* __restrict__ A, int Ka, const float* __restrict__ B,
                 const float* __restrict__ b2, float* __restrict__ Mout,
                 float* __restrict__ vout) {
    int j  = threadIdx.x & 127;
    int di = threadIdx.x >> 7;
    if (blockIdx.x == 64) {
        if (threadIdx.x < 128) {
            float acc = 0.f;
            for (int k = 0; k < Ka; ++k) acc = fmaf(b2[k], B[k * 128 + j], acc);
            vout[j] = acc;
        }
        return;
    }
    int i = blockIdx.x * 2 + di;
    float acc = 0.f;
    for (int k = 0; k < Ka; ++k) acc = fmaf(A[i * Ka + k], B[k * 128 + j], acc);
    Mout[i * 128 + j] = acc;
}

// ---------------------------------------------------------------------------
// fp32 GEMM: C = act(A1@B1 + A2@B2 + bias + rowmask*bias2)
// A row-major [M,K], B row-major [K,N]. 64x64 tile, 256 thr, 4x4 micro-tile.
// K1,K2 must be multiples of 16. B2/A2 optional via K2=0. bias2 optional.
// ---------------------------------------------------------------------------
template <bool RELU>
__global__ __launch_bounds__(256)
void gemm_kernel(const float* __restrict__ A1, const float* __restrict__ B1, int K1,
                 const float* __restrict__ A2, const float* __restrict__ B2, int K2,
                 const float* __restrict__ bias, const float* __restrict__ bias2,
                 const float* __restrict__ rowmask,
                 float* __restrict__ C, int M, int N) {
    __shared__ float As[16][68];   // [k][m], +4 pad keeps b128 alignment, kills conflicts
    __shared__ float Bs[16][64];   // [k][n]
    int tid  = threadIdx.x;
    int tm   = tid >> 4, tn = tid & 15;
    int arow = tid >> 2, ac4 = (tid & 3) << 2;
    int brow = tid >> 4, bc4 = (tid & 15) << 2;
    int rowBase = blockIdx.x * 64, colBase = blockIdx.y * 64;
    float acc[4][4] = {};

    for (int s = 0; s < 2; ++s) {
        const float* A = s ? A2 : A1;
        const float* B = s ? B2 : B1;
        int K = s ? K2 : K1;
        if (K == 0) continue;
        for (int k0 = 0; k0 < K; k0 += 16) {
            float4 av = {0.f, 0.f, 0.f, 0.f};
            int gr = rowBase + arow;
            if (gr < M) av = *(const float4*)(A + gr * K + k0 + ac4);
            float4 bv = {0.f, 0.f, 0.f, 0.f};
            int gc = colBase + bc4;
            const float* Bp = B + (k0 + brow) * N;
            if (gc + 3 < N) bv = *(const float4*)(Bp + gc);
            else {
                if (gc     < N) bv.x = Bp[gc];
                if (gc + 1 < N) bv.y = Bp[gc + 1];
                if (gc + 2 < N) bv.z = Bp[gc + 2];
            }
            __syncthreads();
            As[ac4 + 0][arow] = av.x;
            As[ac4 + 1][arow] = av.y;
            As[ac4 + 2][arow] = av.z;
            As[ac4 + 3][arow] = av.w;
            *(float4*)&Bs[brow][bc4] = bv;
            __syncthreads();
#pragma unroll
            for (int k = 0; k < 16; ++k) {
                float4 a = *(const float4*)&As[k][tm << 2];
                float4 b = *(const float4*)&Bs[k][tn << 2];
                acc[0][0] = fmaf(a.x, b.x, acc[0][0]);
                acc[0][1] = fmaf(a.x, b.y, acc[0][1]);
                acc[0][2] = fmaf(a.x, b.z, acc[0][2]);
                acc[0][3] = fmaf(a.x, b.w, acc[0][3]);
                acc[1][0] = fmaf(a.y, b.x, acc[1][0]);
                acc[1][1] = fmaf(a.y, b.y, acc[1][1]);
                acc[1][2] = fmaf(a.y, b.z, acc[1][2]);
                acc[1][3] = fmaf(a.y, b.w, acc[1][3]);
                acc[2][0] = fmaf(a.z, b.x, acc[2][0]);
                acc[2][1] = fmaf(a.z, b.y, acc[2][1]);
                acc[2][2] = fmaf(a.z, b.z, acc[2][2]);
                acc[2][3] = fmaf(a.z, b.w, acc[2][3]);
                acc[3][0] = fmaf(a.w, b.x, acc[3][0]);
                acc[3][1] = fmaf(a.w, b.y, acc[3][1]);
                acc[3][2] = fmaf(a.w, b.z, acc[3][2]);
                acc[3][3] = fmaf(a.w, b.w, acc[3][3]);
            }
        }
    }

#pragma unroll
    for (int i = 0; i < 4; ++i) {
        int row = rowBase + (tm << 2) + i;
        if (row >= M) continue;
        float rm = rowmask ? rowmask[row] : 0.f;
#pragma unroll
        for (int j = 0; j < 4; ++j) {
            int col = colBase + (tn << 2) + j;
            if (col >= N) continue;
            float v = acc[i][j] + bias[col];
            if (bias2) v = fmaf(rm, bias2[col], v);
            if (RELU) v = fmaxf(v, 0.f);
            C[row * N + col] = v;
        }
    }
}

// ---------------------------------------------------------------------------
// proj = z2 @ W[128x2] + b
// ---------------------------------------------------------------------------
__global__ void proj_kernel(const float* __restrict__ z2, const float* __restrict__ w,
                            const float* __restrict__ b, float* __restrict__ proj, int M) {
    int n = blockIdx.x * blockDim.x + threadIdx.x;
    if (n >= M) return;
    float a0 = b[0], a1 = b[1];
    for (int k = 0; k < 128; ++k) {
        float zz = z2[n * 128 + k];
        a0 = fmaf(zz, w[2 * k], a0);
        a1 = fmaf(zz, w[2 * k + 1], a1);
    }
    proj[2 * n]     = a0;
    proj[2 * n + 1] = a1;
}

__global__ void dist_kernel(const float* __restrict__ proj, const int* __restrict__ idxs,
                            float* __restrict__ out, int e) {
    int i = blockIdx.x * blockDim.x + threadIdx.x;
    if (i >= e) return;
    int n = i / KNB;
    int m = idxs[i];
    float dx = proj[2 * n] - proj[2 * m];
    float dy = proj[2 * n + 1] - proj[2 * m + 1];
    out[i] = dx * dx + dy * dy;
}

// ---------------------------------------------------------------------------
extern "C" void kernel_launch(void* const* d_in, const int* in_sizes, int n_in,
                              void* d_out, int out_size, void* d_ws, size_t ws_size,
                              hipStream_t stream) {
    (void)in_sizes; (void)n_in; (void)out_size; (void)ws_size;
    const float* x    = (const float*)d_in[0];
    const float* eatt = (const float*)d_in[1];
    const int*   idxs = (const int*)d_in[2];
    const float* mw1  = (const float*)d_in[3];
    const float* mb1  = (const float*)d_in[4];
    const float* mw2  = (const float*)d_in[5];
    const float* mb2  = (const float*)d_in[6];
    const float* nw1  = (const float*)d_in[7];
    const float* nb1  = (const float*)d_in[8];
    const float* nw2  = (const float*)d_in[9];
    const float* nb2  = (const float*)d_in[10];
    const float* m2w1 = (const float*)d_in[11];
    const float* m2b1 = (const float*)d_in[12];
    const float* m2w2 = (const float*)d_in[13];
    const float* m2b2 = (const float*)d_in[14];
    const float* n2w1 = (const float*)d_in[15];
    const float* n2b1 = (const float*)d_in[16];
    const float* n2w2 = (const float*)d_in[17];
    const float* n2b2 = (const float*)d_in[18];
    float* out = (float*)d_out;

    float* fws   = (float*)d_ws;
    float* u     = fws;                  // 10000*128
    float* meanh = fws + 1280000;        // 10000*128
    float* z     = fws + 2560000;        // 10000*128
    float* h     = fws + 3840000;        // 10000*128
    float* proj  = fws + 5120000;        // 10000*2
    float* maskv = fws + 5140000;        // 10000
    float* eas   = fws + 5150000;        // 150000
    float* M1    = fws + 5300000;        // 128*128
    float* v1    = fws + 5316384;        // 128
    float* M2    = fws + 5316512;        // 128*128
    float* v2    = fws + 5332896;        // 128
    int*   cnt   = (int*)(fws + 5333024);
    int*   eoff  = cnt + N_NODES;
    int*   fill  = eoff + N_NODES;

    hipMemsetAsync(cnt,  0, N_NODES * sizeof(int), stream);
    hipMemsetAsync(fill, 0, N_NODES * sizeof(int), stream);

    int egrid = (E_EDGES + 255) / 256;
    count_kernel<<<egrid, 256, 0, stream>>>(idxs, cnt, E_EDGES);
    scan_kernel<<<1, 1024, 0, stream>>>(cnt, eoff, N_NODES);
    fill_kernel<<<egrid, 256, 0, stream>>>(idxs, eatt, eoff, fill, eas, E_EDGES);

    dim3 g((N_NODES + 63) / 64, 2);

    // ---- Layer 1 ----
    // u1 = x @ mw1[:784] + mb1
    gemm_kernel<false><<<g, 256, 0, stream>>>(x, mw1, 784, nullptr, nullptr, 0,
                                              mb1, nullptr, nullptr, u, N_NODES, 128);
    // meanh1 = mean_e relu(u1 + ea*mw1[784]) per node
    msg_reduce_kernel<<<N_NODES, 128, 0, stream>>>(u, mw1 + 784 * 128, eas, eoff, cnt,
                                                   meanh, maskv);
    // M1 = mw2 @ nw1[784:], v1 = mb2 @ nw1[784:]
    wmix_kernel<<<65, 256, 0, stream>>>(mw2, 784, nw1 + 784 * 128, mb2, M1, v1);
    // z1 = relu(x @ nw1[:784] + meanh1 @ M1 + mask*v1 + nb1)
    gemm_kernel<true><<<g, 256, 0, stream>>>(x, nw1, 784, meanh, M1, 128,
                                             nb1, v1, maskv, z, N_NODES, 128);
    // h = z1 @ nw2 + nb2
    gemm_kernel<false><<<g, 256, 0, stream>>>(z, nw2, 128, nullptr, nullptr, 0,
                                              nb2, nullptr, nullptr, h, N_NODES, 128);

    // ---- Layer 2 ----
    gemm_kernel<false><<<g, 256, 0, stream>>>(h, m2w1, 128, nullptr, nullptr, 0,
                                              m2b1, nullptr, nullptr, u, N_NODES, 128);
    msg_reduce_kernel<<<N_NODES, 128, 0, stream>>>(u, m2w1 + 128 * 128, eas, eoff, cnt,
                                                   meanh, maskv);
    wmix_kernel<<<65, 256, 0, stream>>>(m2w2, 128, n2w1 + 128 * 128, m2b2, M2, v2);
    gemm_kernel<true><<<g, 256, 0, stream>>>(h, n2w1, 128, meanh, M2, 128,
                                             n2b1, v2, maskv, z, N_NODES, 128);

    proj_kernel<<<(N_NODES + 255) / 256, 256, 0, stream>>>(z, n2w2, n2b2, proj, N_NODES);
    dist_kernel<<<egrid, 256, 0, stream>>>(proj, idxs, out, E_EDGES);
}

// Round 2
// 399.814 us; speedup vs baseline: 1.3999x; 1.3999x over previous
//
#include <hip/hip_runtime.h>

#define N_NODES 10000
#define E_EDGES 150000
#define KNB     15

// ---------------------------------------------------------------------------
// CSR build: count -> scan -> fill (groups edge_attr scalars by src node)
// ---------------------------------------------------------------------------
__global__ void count_kernel(const int* __restrict__ idxs, int* __restrict__ cnt, int e) {
    int i = blockIdx.x * blockDim.x + threadIdx.x;
    if (i < e) atomicAdd(&cnt[idxs[i]], 1);
}

__global__ void scan_kernel(const int* __restrict__ cnt, int* __restrict__ eoff, int n) {
    __shared__ int lds[1024];
    __shared__ int carry_s;
    if (threadIdx.x == 0) carry_s = 0;
    __syncthreads();
    for (int base = 0; base < n; base += 1024) {
        int i = base + (int)threadIdx.x;
        int v = (i < n) ? cnt[i] : 0;
        lds[threadIdx.x] = v;
        __syncthreads();
        for (int off = 1; off < 1024; off <<= 1) {
            int t = 0;
            if (threadIdx.x >= (unsigned)off) t = lds[threadIdx.x - off];
            __syncthreads();
            if (threadIdx.x >= (unsigned)off) lds[threadIdx.x] += t;
            __syncthreads();
        }
        int incl  = lds[threadIdx.x];
        int total = lds[1023];
        if (i < n) eoff[i] = carry_s + incl - v;   // exclusive prefix
        __syncthreads();
        if (threadIdx.x == 0) carry_s += total;
        __syncthreads();
    }
}

__global__ void fill_kernel(const int* __restrict__ idxs, const float* __restrict__ ea,
                            const int* __restrict__ eoff, int* __restrict__ fill,
                            float* __restrict__ eas, int e) {
    int i = blockIdx.x * blockDim.x + threadIdx.x;
    if (i < e) {
        int s = idxs[i];
        int p = atomicAdd(&fill[s], 1);
        eas[eoff[s] + p] = ea[i];
    }
}

// ---------------------------------------------------------------------------
// Per-node message reduce: meanh[n][d] = mean_e relu(u[n][d] + ea_e * w[d])
// ---------------------------------------------------------------------------
__global__ __launch_bounds__(128)
void msg_reduce_kernel(const float* __restrict__ u, const float* __restrict__ wlast,
                       const float* __restrict__ eas, const int* __restrict__ eoff,
                       const int* __restrict__ cnt, float* __restrict__ meanh,
                       float* __restrict__ maskv) {
    int n = blockIdx.x, d = threadIdx.x;
    __shared__ float es[128];
    int c = cnt[n], base = eoff[n];
    float uu = u[n * 128 + d];
    float w  = wlast[d];
    float s  = 0.f;
    for (int st = 0; st < c; st += 128) {
        __syncthreads();
        if (st + d < c) es[d] = eas[base + st + d];
        __syncthreads();
        int m = min(128, c - st);
        for (int j = 0; j < m; ++j) s += fmaxf(fmaf(es[j], w, uu), 0.f);
    }
    meanh[n * 128 + d] = (c > 0) ? s / (float)c : 0.f;
    if (d == 0) maskv[n] = (c > 0) ? 1.f : 0.f;
}

// ---------------------------------------------------------------------------
// vrow: vout[j] = sum_k b2[k] * B[k*128+j]  — block-parallel reduction per j
// ---------------------------------------------------------------------------
__global__ __launch_bounds__(256)
void vrow_kernel(const float* __restrict__ b2, int Ka, const float* __restrict__ B,
                 float* __restrict__ vout) {
    int j = blockIdx.x;               // 128 blocks, one output each
    __shared__ float red[256];
    float acc = 0.f;
    for (int k = threadIdx.x; k < Ka; k += 256)
        acc = fmaf(b2[k], B[k * 128 + j], acc);
    red[threadIdx.x] = acc;
    __syncthreads();
    for (int off = 128; off > 0; off >>= 1) {
        if (threadIdx.x < (unsigned)off) red[threadIdx.x] += red[threadIdx.x + off];
        __syncthreads();
    }
    if (threadIdx.x == 0) vout[j] = red[0];
}

// ---------------------------------------------------------------------------
// fp32 GEMM: C = act(A1@B1 + A2@B2 + bias + rowmask*bias2)
// A row-major [M,K], B row-major [K,N]. 64x64 tile, 256 thr, 4x4 micro-tile.
// K1,K2 must be multiples of 16. A2/B2 optional via K2=0. bias/bias2 optional.
// ---------------------------------------------------------------------------
template <bool RELU>
__global__ __launch_bounds__(256)
void gemm_kernel(const float* __restrict__ A1, const float* __restrict__ B1, int K1,
                 const float* __restrict__ A2, const float* __restrict__ B2, int K2,
                 const float* __restrict__ bias, const float* __restrict__ bias2,
                 const float* __restrict__ rowmask,
                 float* __restrict__ C, int M, int N) {
    __shared__ float As[16][68];   // [k][m], +4 pad keeps b128 alignment, kills conflicts
    __shared__ float Bs[16][64];   // [k][n]
    int tid  = threadIdx.x;
    int tm   = tid >> 4, tn = tid & 15;
    int arow = tid >> 2, ac4 = (tid & 3) << 2;
    int brow = tid >> 4, bc4 = (tid & 15) << 2;
    int rowBase = blockIdx.x * 64, colBase = blockIdx.y * 64;
    float acc[4][4] = {};

    for (int s = 0; s < 2; ++s) {
        const float* A = s ? A2 : A1;
        const float* B = s ? B2 : B1;
        int K = s ? K2 : K1;
        if (K == 0) continue;
        for (int k0 = 0; k0 < K; k0 += 16) {
            float4 av = {0.f, 0.f, 0.f, 0.f};
            int gr = rowBase + arow;
            if (gr < M) av = *(const float4*)(A + gr * K + k0 + ac4);
            float4 bv = {0.f, 0.f, 0.f, 0.f};
            int gc = colBase + bc4;
            const float* Bp = B + (k0 + brow) * N;
            if (gc + 3 < N) bv = *(const float4*)(Bp + gc);
            else {
                if (gc     < N) bv.x = Bp[gc];
                if (gc + 1 < N) bv.y = Bp[gc + 1];
                if (gc + 2 < N) bv.z = Bp[gc + 2];
            }
            __syncthreads();
            As[ac4 + 0][arow] = av.x;
            As[ac4 + 1][arow] = av.y;
            As[ac4 + 2][arow] = av.z;
            As[ac4 + 3][arow] = av.w;
            *(float4*)&Bs[brow][bc4] = bv;
            __syncthreads();
#pragma unroll
            for (int k = 0; k < 16; ++k) {
                float4 a = *(const float4*)&As[k][tm << 2];
                float4 b = *(const float4*)&Bs[k][tn << 2];
                acc[0][0] = fmaf(a.x, b.x, acc[0][0]);
                acc[0][1] = fmaf(a.x, b.y, acc[0][1]);
                acc[0][2] = fmaf(a.x, b.z, acc[0][2]);
                acc[0][3] = fmaf(a.x, b.w, acc[0][3]);
                acc[1][0] = fmaf(a.y, b.x, acc[1][0]);
                acc[1][1] = fmaf(a.y, b.y, acc[1][1]);
                acc[1][2] = fmaf(a.y, b.z, acc[1][2]);
                acc[1][3] = fmaf(a.y, b.w, acc[1][3]);
                acc[2][0] = fmaf(a.z, b.x, acc[2][0]);
                acc[2][1] = fmaf(a.z, b.y, acc[2][1]);
                acc[2][2] = fmaf(a.z, b.z, acc[2][2]);
                acc[2][3] = fmaf(a.z, b.w, acc[2][3]);
                acc[3][0] = fmaf(a.w, b.x, acc[3][0]);
                acc[3][1] = fmaf(a.w, b.y, acc[3][1]);
                acc[3][2] = fmaf(a.w, b.z, acc[3][2]);
                acc[3][3] = fmaf(a.w, b.w, acc[3][3]);
            }
        }
    }

#pragma unroll
    for (int i = 0; i < 4; ++i) {
        int row = rowBase + (tm << 2) + i;
        if (row >= M) continue;
        float rm = rowmask ? rowmask[row] : 0.f;
#pragma unroll
        for (int j = 0; j < 4; ++j) {
            int col = colBase + (tn << 2) + j;
            if (col >= N) continue;
            float v = acc[i][j] + (bias ? bias[col] : 0.f);
            if (bias2) v = fmaf(rm, bias2[col], v);
            if (RELU) v = fmaxf(v, 0.f);
            C[row * N + col] = v;
        }
    }
}

// ---------------------------------------------------------------------------
// proj = z2 @ W[128x2] + b — one wave per node, coalesced, shuffle reduce
// ---------------------------------------------------------------------------
__global__ __launch_bounds__(256)
void proj_kernel(const float* __restrict__ z2, const float* __restrict__ w,
                 const float* __restrict__ b, float* __restrict__ proj, int M) {
    int wv = threadIdx.x >> 6, lane = threadIdx.x & 63;
    int n  = blockIdx.x * 4 + wv;
    if (n >= M) return;
    float2 zz = *(const float2*)(z2 + n * 128 + 2 * lane);
    float4 wq = *(const float4*)(w + 4 * lane);   // (w0[2l], w1[2l], w0[2l+1], w1[2l+1])
    float a0 = fmaf(zz.y, wq.z, zz.x * wq.x);
    float a1 = fmaf(zz.y, wq.w, zz.x * wq.y);
    for (int off = 32; off > 0; off >>= 1) {
        a0 += __shfl_down(a0, off, 64);
        a1 += __shfl_down(a1, off, 64);
    }
    if (lane == 0) {
        proj[2 * n]     = a0 + b[0];
        proj[2 * n + 1] = a1 + b[1];
    }
}

__global__ void dist_kernel(const float* __restrict__ proj, const int* __restrict__ idxs,
                            float* __restrict__ out, int e) {
    int i = blockIdx.x * blockDim.x + threadIdx.x;
    if (i >= e) return;
    int n = i / KNB;
    int m = idxs[i];
    float dx = proj[2 * n] - proj[2 * m];
    float dy = proj[2 * n + 1] - proj[2 * m + 1];
    out[i] = dx * dx + dy * dy;
}

// ---------------------------------------------------------------------------
extern "C" void kernel_launch(void* const* d_in, const int* in_sizes, int n_in,
                              void* d_out, int out_size, void* d_ws, size_t ws_size,
                              hipStream_t stream) {
    (void)in_sizes; (void)n_in; (void)out_size; (void)ws_size;
    const float* x    = (const float*)d_in[0];
    const float* eatt = (const float*)d_in[1];
    const int*   idxs = (const int*)d_in[2];
    const float* mw1  = (const float*)d_in[3];
    const float* mb1  = (const float*)d_in[4];
    const float* mw2  = (const float*)d_in[5];
    const float* mb2  = (const float*)d_in[6];
    const float* nw1  = (const float*)d_in[7];
    const float* nb1  = (const float*)d_in[8];
    const float* nw2  = (const float*)d_in[9];
    const float* nb2  = (const float*)d_in[10];
    const float* m2w1 = (const float*)d_in[11];
    const float* m2b1 = (const float*)d_in[12];
    const float* m2w2 = (const float*)d_in[13];
    const float* m2b2 = (const float*)d_in[14];
    const float* n2w1 = (const float*)d_in[15];
    const float* n2b1 = (const float*)d_in[16];
    const float* n2w2 = (const float*)d_in[17];
    const float* n2b2 = (const float*)d_in[18];
    float* out = (float*)d_out;

    float* fws   = (float*)d_ws;
    float* u     = fws;                  // 10000*128
    float* meanh = fws + 1280000;        // 10000*128
    float* z     = fws + 2560000;        // 10000*128
    float* h     = fws + 3840000;        // 10000*128
    float* proj  = fws + 5120000;        // 10000*2
    float* maskv = fws + 5140000;        // 10000
    float* eas   = fws + 5150000;        // 150000
    float* M1    = fws + 5300000;        // 128*128
    float* v1    = fws + 5316384;        // 128
    float* M2    = fws + 5316512;        // 128*128
    float* v2    = fws + 5332896;        // 128
    int*   cnt   = (int*)(fws + 5333024);
    int*   eoff  = cnt + N_NODES;
    int*   fill  = eoff + N_NODES;

    hipMemsetAsync(cnt,  0, N_NODES * sizeof(int), stream);
    hipMemsetAsync(fill, 0, N_NODES * sizeof(int), stream);

    int egrid = (E_EDGES + 255) / 256;
    count_kernel<<<egrid, 256, 0, stream>>>(idxs, cnt, E_EDGES);
    scan_kernel<<<1, 1024, 0, stream>>>(cnt, eoff, N_NODES);
    fill_kernel<<<egrid, 256, 0, stream>>>(idxs, eatt, eoff, fill, eas, E_EDGES);

    dim3 g((N_NODES + 63) / 64, 2);
    dim3 gw(2, 2);                       // weight-fold grids (128x128)

    // ---- Layer 1 ----
    // u1 = x @ mw1[:784] + mb1
    gemm_kernel<false><<<g, 256, 0, stream>>>(x, mw1, 784, nullptr, nullptr, 0,
                                              mb1, nullptr, nullptr, u, N_NODES, 128);
    // meanh1 = mean_e relu(u1 + ea*mw1[784]) per node
    msg_reduce_kernel<<<N_NODES, 128, 0, stream>>>(u, mw1 + 784 * 128, eas, eoff, cnt,
                                                   meanh, maskv);
    // M1 = mw2 @ nw1[784:]  (tiled GEMM, was the 260 us wmix stall)
    gemm_kernel<false><<<gw, 256, 0, stream>>>(mw2, nw1 + 784 * 128, 784,
                                               nullptr, nullptr, 0,
                                               nullptr, nullptr, nullptr, M1, 128, 128);
    // v1 = mb2 @ nw1[784:]
    vrow_kernel<<<128, 256, 0, stream>>>(mb2, 784, nw1 + 784 * 128, v1);
    // z1 = relu(x @ nw1[:784] + meanh1 @ M1 + mask*v1 + nb1)
    gemm_kernel<true><<<g, 256, 0, stream>>>(x, nw1, 784, meanh, M1, 128,
                                             nb1, v1, maskv, z, N_NODES, 128);
    // h = z1 @ nw2 + nb2
    gemm_kernel<false><<<g, 256, 0, stream>>>(z, nw2, 128, nullptr, nullptr, 0,
                                              nb2, nullptr, nullptr, h, N_NODES, 128);

    // ---- Layer 2 ----
    gemm_kernel<false><<<g, 256, 0, stream>>>(h, m2w1, 128, nullptr, nullptr, 0,
                                              m2b1, nullptr, nullptr, u, N_NODES, 128);
    msg_reduce_kernel<<<N_NODES, 128, 0, stream>>>(u, m2w1 + 128 * 128, eas, eoff, cnt,
                                                   meanh, maskv);
    gemm_kernel<false><<<gw, 256, 0, stream>>>(m2w2, n2w1 + 128 * 128, 128,
                                               nullptr, nullptr, 0,
                                               nullptr, nullptr, nullptr, M2, 128, 128);
    vrow_kernel<<<128, 256, 0, stream>>>(m2b2, 128, n2w1 + 128 * 128, v2);
    gemm_kernel<true><<<g, 256, 0, stream>>>(h, n2w1, 128, meanh, M2, 128,
                                             n2b1, v2, maskv, z, N_NODES, 128);

    proj_kernel<<<(N_NODES + 3) / 4, 256, 0, stream>>>(z, n2w2, n2b2, proj, N_NODES);
    dist_kernel<<<egrid, 256, 0, stream>>>(proj, idxs, out, E_EDGES);
}

// Round 3
// 308.468 us; speedup vs baseline: 1.8145x; 1.2961x over previous
//
#include <hip/hip_runtime.h>

#define N_NODES 10000
#define E_EDGES 150000
#define KNB     15

// ---------------------------------------------------------------------------
// CSR build: count -> scan(+maskv) -> fill
// ---------------------------------------------------------------------------
__global__ void count_kernel(const int* __restrict__ idxs, int* __restrict__ cnt, int e) {
    int i = blockIdx.x * blockDim.x + threadIdx.x;
    if (i < e) atomicAdd(&cnt[idxs[i]], 1);
}

__global__ void scan_kernel(const int* __restrict__ cnt, int* __restrict__ eoff,
                            float* __restrict__ maskv, int n) {
    __shared__ int lds[1024];
    __shared__ int carry_s;
    if (threadIdx.x == 0) carry_s = 0;
    __syncthreads();
    for (int base = 0; base < n; base += 1024) {
        int i = base + (int)threadIdx.x;
        int v = (i < n) ? cnt[i] : 0;
        lds[threadIdx.x] = v;
        __syncthreads();
        for (int off = 1; off < 1024; off <<= 1) {
            int t = 0;
            if (threadIdx.x >= (unsigned)off) t = lds[threadIdx.x - off];
            __syncthreads();
            if (threadIdx.x >= (unsigned)off) lds[threadIdx.x] += t;
            __syncthreads();
        }
        int incl  = lds[threadIdx.x];
        int total = lds[1023];
        if (i < n) {
            eoff[i]  = carry_s + incl - v;   // exclusive prefix
            maskv[i] = (v > 0) ? 1.f : 0.f;
        }
        __syncthreads();
        if (threadIdx.x == 0) carry_s += total;
        __syncthreads();
    }
}

__global__ void fill_kernel(const int* __restrict__ idxs, const float* __restrict__ ea,
                            const int* __restrict__ eoff, int* __restrict__ fill,
                            float* __restrict__ eas, int e) {
    int i = blockIdx.x * blockDim.x + threadIdx.x;
    if (i < e) {
        int s = idxs[i];
        int p = atomicAdd(&fill[s], 1);
        eas[eoff[s] + p] = ea[i];
    }
}

// ---------------------------------------------------------------------------
// Per-node message reduce: meanh[n][d] = mean_e relu(u[n][d] + ea_e * w[d])
// u is the first 128 cols of a row-stride-256 buffer.
// ---------------------------------------------------------------------------
__global__ __launch_bounds__(128)
void msg_reduce_kernel(const float* __restrict__ u, const float* __restrict__ wlast,
                       const float* __restrict__ eas, const int* __restrict__ eoff,
                       const int* __restrict__ cnt, float* __restrict__ meanh) {
    int n = blockIdx.x, d = threadIdx.x;
    __shared__ float es[128];
    int c = cnt[n], base = eoff[n];
    float uu = u[n * 256 + d];
    float w  = wlast[d];
    float s  = 0.f;
    for (int st = 0; st < c; st += 128) {
        __syncthreads();
        if (st + d < c) es[d] = eas[base + st + d];
        __syncthreads();
        int m = min(128, c - st);
        for (int j = 0; j < m; ++j) s += fmaxf(fmaf(es[j], w, uu), 0.f);
    }
    meanh[n * 128 + d] = (c > 0) ? s / (float)c : 0.f;
}

// ---------------------------------------------------------------------------
// Generic fp32 GEMM tile, TM=MR*16 x 64, 256 threads, prefetched K-loop.
// C[:, col<128 half] uses Blo/biasLo; col>=128 half uses Bhi/biasHi (+rowmask*vhi).
// Optional elementwise addend (stride addLd, indexed by global col).
// K must be a multiple of 16. Row guard on M only; N exact multiple of 64.
// ---------------------------------------------------------------------------
template <int MR> struct AVecT;
template <> struct AVecT<4> { using T = float4; };
template <> struct AVecT<2> { using T = float2; };

template <int MR, bool RELU>
__device__ __forceinline__
void gemm_tile(const float* __restrict__ A, int K,
               const float* __restrict__ Blo, const float* __restrict__ Bhi, int ldB,
               const float* __restrict__ biasLo, const float* __restrict__ biasHi,
               const float* __restrict__ vhi, const float* __restrict__ rowmask,
               const float* __restrict__ addend, int addLd,
               float* __restrict__ C, int ldC, int M,
               int rowBlk, int colBlk) {
    constexpr int TM  = MR * 16;
    constexpr int PAD = (MR == 4) ? 4 : 2;
    using AVec = typename AVecT<MR>::T;
    __shared__ float As[16][TM + PAD];
    __shared__ float Bs[16][64];

    int tid = threadIdx.x;
    int tn  = tid & 15, tm = tid >> 4;
    int arow, acB;
    if (MR == 4) { arow = tid >> 2; acB = (tid & 3) << 2; }
    else         { arow = tid >> 3; acB = (tid & 7) << 1; }
    int brow = tid >> 4, bcol = (tid & 15) << 2;
    int rowBase = rowBlk * TM, colBase = colBlk * 64;

    bool half = (Bhi != nullptr) && (colBase >= 128);
    const float* B    = half ? Bhi : Blo;
    const float* bias = half ? biasHi : biasLo;
    int bj = colBase - (half ? 128 : 0) + bcol;

    AVec av; float4 bv;
    auto loadA = [&](int k0, AVec& dst) {
        int gr = rowBase + arow;
        if (gr < M) dst = *(const AVec*)(A + (size_t)gr * K + k0 + acB);
        else {
            if (MR == 4) { float4* p = (float4*)&dst; p->x = p->y = p->z = p->w = 0.f; }
            else         { float2* p = (float2*)&dst; p->x = p->y = 0.f; }
        }
    };
    auto loadB = [&](int k0, float4& dst) {
        dst = *(const float4*)(B + (size_t)(k0 + brow) * ldB + bj);
    };
    loadA(0, av); loadB(0, bv);

    float acc[MR][4] = {};
    for (int k0 = 0; k0 < K; k0 += 16) {
        __syncthreads();
        if (MR == 4) {
            float4 a4 = *(float4*)&av;
            As[acB + 0][arow] = a4.x; As[acB + 1][arow] = a4.y;
            As[acB + 2][arow] = a4.z; As[acB + 3][arow] = a4.w;
        } else {
            float2 a2 = *(float2*)&av;
            As[acB + 0][arow] = a2.x; As[acB + 1][arow] = a2.y;
        }
        *(float4*)&Bs[brow][bcol] = bv;
        __syncthreads();
        if (k0 + 16 < K) { loadA(k0 + 16, av); loadB(k0 + 16, bv); }   // prefetch
#pragma unroll
        for (int k = 0; k < 16; ++k) {
            float4 b = *(const float4*)&Bs[k][tn << 2];
            if (MR == 4) {
                float4 a = *(const float4*)&As[k][tm << 2];
                acc[0][0] = fmaf(a.x, b.x, acc[0][0]); acc[0][1] = fmaf(a.x, b.y, acc[0][1]);
                acc[0][2] = fmaf(a.x, b.z, acc[0][2]); acc[0][3] = fmaf(a.x, b.w, acc[0][3]);
                acc[1][0] = fmaf(a.y, b.x, acc[1][0]); acc[1][1] = fmaf(a.y, b.y, acc[1][1]);
                acc[1][2] = fmaf(a.y, b.z, acc[1][2]); acc[1][3] = fmaf(a.y, b.w, acc[1][3]);
                acc[2][0] = fmaf(a.z, b.x, acc[2][0]); acc[2][1] = fmaf(a.z, b.y, acc[2][1]);
                acc[2][2] = fmaf(a.z, b.z, acc[2][2]); acc[2][3] = fmaf(a.z, b.w, acc[2][3]);
                acc[3][0] = fmaf(a.w, b.x, acc[3][0]); acc[3][1] = fmaf(a.w, b.y, acc[3][1]);
                acc[3][2] = fmaf(a.w, b.z, acc[3][2]); acc[3][3] = fmaf(a.w, b.w, acc[3][3]);
            } else {
                float2 a = *(const float2*)&As[k][tm << 1];
                acc[0][0] = fmaf(a.x, b.x, acc[0][0]); acc[0][1] = fmaf(a.x, b.y, acc[0][1]);
                acc[0][2] = fmaf(a.x, b.z, acc[0][2]); acc[0][3] = fmaf(a.x, b.w, acc[0][3]);
                acc[1][0] = fmaf(a.y, b.x, acc[1][0]); acc[1][1] = fmaf(a.y, b.y, acc[1][1]);
                acc[1][2] = fmaf(a.y, b.z, acc[1][2]); acc[1][3] = fmaf(a.y, b.w, acc[1][3]);
            }
        }
    }

#pragma unroll
    for (int i = 0; i < MR; ++i) {
        int row = rowBase + tm * MR + i;
        if (row >= M) continue;
        float rm = rowmask ? rowmask[row] : 0.f;
#pragma unroll
        for (int j = 0; j < 4; ++j) {
            int gcol = colBase + (tn << 2) + j;
            int cj   = gcol - (half ? 128 : 0);
            float v = acc[i][j];
            if (bias) v += bias[cj];
            if (half && vhi) v = fmaf(rm, vhi[cj], v);
            if (addend) v += addend[(size_t)row * addLd + gcol];
            if (RELU) v = fmaxf(v, 0.f);
            C[(size_t)row * ldC + gcol] = v;
        }
    }
}

template <int MR, bool RELU>
__global__ __launch_bounds__(256)
void gemm_kernel(const float* __restrict__ A, int K,
                 const float* __restrict__ Blo, const float* __restrict__ Bhi, int ldB,
                 const float* __restrict__ biasLo, const float* __restrict__ biasHi,
                 const float* __restrict__ vhi, const float* __restrict__ rowmask,
                 const float* __restrict__ addend, int addLd,
                 float* __restrict__ C, int ldC, int M) {
    gemm_tile<MR, RELU>(A, K, Blo, Bhi, ldB, biasLo, biasHi, vhi, rowmask,
                        addend, addLd, C, ldC, M, blockIdx.x, blockIdx.y);
}

// ---------------------------------------------------------------------------
// One-launch weight folds:
//  blocks [0,8):   M1 = mw2 @ nw1[784:]           (K=784)
//  blocks [8,16):  M2 = m2w2 @ n2w1[128:]         (K=128)
//  blocks [16,32): WH[:, :128] = nw2 @ m2w1[:128]; WH[:,128:] = nw2 @ n2w1[:128]
//  blocks [32,40): vrow tasks: v1, v2, bu2(+m2b1), bx2(+n2b1)
// ---------------------------------------------------------------------------
__global__ __launch_bounds__(256)
void fold_kernel(const float* __restrict__ mw2, const float* __restrict__ mb2,
                 const float* __restrict__ nw1, const float* __restrict__ nb2,
                 const float* __restrict__ nw2,
                 const float* __restrict__ m2w1, const float* __restrict__ m2b1,
                 const float* __restrict__ m2w2, const float* __restrict__ m2b2,
                 const float* __restrict__ n2w1, const float* __restrict__ n2b1,
                 float* __restrict__ M1, float* __restrict__ M2, float* __restrict__ WH,
                 float* __restrict__ v1, float* __restrict__ v2,
                 float* __restrict__ bu2, float* __restrict__ bx2) {
    int b = blockIdx.x;
    if (b < 8) {
        gemm_tile<2, false>(mw2, 784, nw1 + 784 * 128, nullptr, 128,
                            nullptr, nullptr, nullptr, nullptr, nullptr, 0,
                            M1, 128, 128, b >> 1, b & 1);
    } else if (b < 16) {
        int t = b - 8;
        gemm_tile<2, false>(m2w2, 128, n2w1 + 128 * 128, nullptr, 128,
                            nullptr, nullptr, nullptr, nullptr, nullptr, 0,
                            M2, 128, 128, t >> 1, t & 1);
    } else if (b < 32) {
        int t = b - 16;
        gemm_tile<2, false>(nw2, 128, m2w1, n2w1, 128,
                            nullptr, nullptr, nullptr, nullptr, nullptr, 0,
                            WH, 256, 128, t >> 2, t & 3);
    } else {
        __shared__ float red[256];
        int t  = (b - 32) >> 1;
        int j  = ((b - 32) & 1) * 64 + (threadIdx.x & 63);
        int kq = threadIdx.x >> 6;
        const float* bvec; const float* Bv; const float* add; float* out; int Kv;
        if (t == 0)      { bvec = mb2;  Bv = nw1 + 784 * 128;  add = nullptr; out = v1;  Kv = 784; }
        else if (t == 1) { bvec = m2b2; Bv = n2w1 + 128 * 128; add = nullptr; out = v2;  Kv = 128; }
        else if (t == 2) { bvec = nb2;  Bv = m2w1;             add = m2b1;    out = bu2; Kv = 128; }
        else             { bvec = nb2;  Bv = n2w1;             add = n2b1;    out = bx2; Kv = 128; }
        float acc = 0.f;
        for (int k = kq; k < Kv; k += 4) acc = fmaf(bvec[k], Bv[k * 128 + j], acc);
        red[threadIdx.x] = acc;
        __syncthreads();
        if (threadIdx.x < 64) {
            float tot = red[threadIdx.x] + red[threadIdx.x + 64] +
                        red[threadIdx.x + 128] + red[threadIdx.x + 192];
            out[j] = tot + (add ? add[j] : 0.f);
        }
    }
}

// ---------------------------------------------------------------------------
// proj = z2 @ W[128x2] + b — one wave per node, shuffle reduce
// ---------------------------------------------------------------------------
__global__ __launch_bounds__(256)
void proj_kernel(const float* __restrict__ z2, const float* __restrict__ w,
                 const float* __restrict__ b, float* __restrict__ proj, int M) {
    int wv = threadIdx.x >> 6, lane = threadIdx.x & 63;
    int n  = blockIdx.x * 4 + wv;
    if (n >= M) return;
    float2 zz = *(const float2*)(z2 + (size_t)n * 128 + 2 * lane);
    float4 wq = *(const float4*)(w + 4 * lane);
    float a0 = fmaf(zz.y, wq.z, zz.x * wq.x);
    float a1 = fmaf(zz.y, wq.w, zz.x * wq.y);
    for (int off = 32; off > 0; off >>= 1) {
        a0 += __shfl_down(a0, off, 64);
        a1 += __shfl_down(a1, off, 64);
    }
    if (lane == 0) {
        proj[2 * n]     = a0 + b[0];
        proj[2 * n + 1] = a1 + b[1];
    }
}

__global__ void dist_kernel(const float* __restrict__ proj, const int* __restrict__ idxs,
                            float* __restrict__ out, int e) {
    int i = blockIdx.x * blockDim.x + threadIdx.x;
    if (i >= e) return;
    int n = i / KNB;
    int m = idxs[i];
    float dx = proj[2 * n] - proj[2 * m];
    float dy = proj[2 * n + 1] - proj[2 * m + 1];
    out[i] = dx * dx + dy * dy;
}

// ---------------------------------------------------------------------------
extern "C" void kernel_launch(void* const* d_in, const int* in_sizes, int n_in,
                              void* d_out, int out_size, void* d_ws, size_t ws_size,
                              hipStream_t stream) {
    (void)in_sizes; (void)n_in; (void)out_size; (void)ws_size;
    const float* x    = (const float*)d_in[0];
    const float* eatt = (const float*)d_in[1];
    const int*   idxs = (const int*)d_in[2];
    const float* mw1  = (const float*)d_in[3];
    const float* mb1  = (const float*)d_in[4];
    const float* mw2  = (const float*)d_in[5];
    const float* mb2  = (const float*)d_in[6];
    const float* nw1  = (const float*)d_in[7];
    const float* nb1  = (const float*)d_in[8];
    const float* nw2  = (const float*)d_in[9];
    const float* nb2  = (const float*)d_in[10];
    const float* m2w1 = (const float*)d_in[11];
    const float* m2b1 = (const float*)d_in[12];
    const float* m2w2 = (const float*)d_in[13];
    const float* m2b2 = (const float*)d_in[14];
    const float* n2w1 = (const float*)d_in[15];
    const float* n2b1 = (const float*)d_in[16];
    const float* n2w2 = (const float*)d_in[17];
    const float* n2b2 = (const float*)d_in[18];
    float* out = (float*)d_out;

    float* fws   = (float*)d_ws;
    float* UX    = fws;                   // 10000*256 (u | xn), reused by layer 2
    float* meanh = fws + 2560000;         // 10000*128, reused by layer 2
    float* zbuf  = fws + 3840000;         // 10000*128 (z1, then z2)
    float* proj  = fws + 5120000;         // 10000*2
    float* maskv = fws + 5140000;         // 10000
    float* eas   = fws + 5150016;         // 150000
    float* M1    = fws + 5300016;         // 128*128
    float* M2    = fws + 5316400;         // 128*128
    float* WH    = fws + 5332784;         // 128*256
    float* v1    = fws + 5365552;         // 128
    float* v2    = fws + 5365680;         // 128
    float* bu2   = fws + 5365808;         // 128
    float* bx2   = fws + 5365936;         // 128
    int*   cnt   = (int*)(fws + 5366064);
    int*   fill  = cnt + N_NODES;
    int*   eoff  = fill + N_NODES;

    hipMemsetAsync(cnt, 0, 2 * N_NODES * sizeof(int), stream);   // cnt + fill

    int egrid = (E_EDGES + 255) / 256;
    count_kernel<<<egrid, 256, 0, stream>>>(idxs, cnt, E_EDGES);
    scan_kernel<<<1, 1024, 0, stream>>>(cnt, eoff, maskv, N_NODES);
    fill_kernel<<<egrid, 256, 0, stream>>>(idxs, eatt, eoff, fill, eas, E_EDGES);

    // all weight-only folds in one launch
    fold_kernel<<<40, 256, 0, stream>>>(mw2, mb2, nw1, nb2, nw2,
                                        m2w1, m2b1, m2w2, m2b2, n2w1, n2b1,
                                        M1, M2, WH, v1, v2, bu2, bx2);

    // GEMM-A: UX = [ x@mw1[:784]+mb1 | x@nw1[:784]+nb1+maskv*v1 ]   (K=784, N=256)
    gemm_kernel<4, false><<<dim3(157, 4), 256, 0, stream>>>(
        x, 784, mw1, nw1, 128, mb1, nb1, v1, maskv, nullptr, 0, UX, 256, N_NODES);

    // meanh1
    msg_reduce_kernel<<<N_NODES, 128, 0, stream>>>(UX, mw1 + 784 * 128, eas, eoff, cnt, meanh);

    // z1 = relu(xn1 + meanh1 @ M1)
    gemm_kernel<2, true><<<dim3(313, 2), 256, 0, stream>>>(
        meanh, 128, M1, nullptr, 128, nullptr, nullptr, nullptr, nullptr,
        UX + 128, 256, zbuf, 128, N_NODES);

    // GEMM-B: UX = [ z1@WHu+bu2 | z1@WHx+bx2+maskv*v2 ]   (K=128, N=256)
    gemm_kernel<2, false><<<dim3(313, 4), 256, 0, stream>>>(
        zbuf, 128, WH, WH + 128, 256, bu2, bx2, v2, maskv, nullptr, 0, UX, 256, N_NODES);

    // meanh2
    msg_reduce_kernel<<<N_NODES, 128, 0, stream>>>(UX, m2w1 + 128 * 128, eas, eoff, cnt, meanh);

    // z2 = relu(xn2 + meanh2 @ M2)
    gemm_kernel<2, true><<<dim3(313, 2), 256, 0, stream>>>(
        meanh, 128, M2, nullptr, 128, nullptr, nullptr, nullptr, nullptr,
        UX + 128, 256, zbuf, 128, N_NODES);

    proj_kernel<<<(N_NODES + 3) / 4, 256, 0, stream>>>(zbuf, n2w2, n2b2, proj, N_NODES);
    dist_kernel<<<egrid, 256, 0, stream>>>(proj, idxs, out, E_EDGES);
}